// Round 14
// baseline (587.818 us; speedup 1.0000x reference)
//
#include <hip/hip_runtime.h>
#include <hip/hip_bf16.h>
#include <math.h>

#define N_TOK 8192
#define HIDD  1024
#define FFND  4096
#define NE    8
#define CAP   2560
#define TMX   20    // CAP/128 (fallback kernel)
#define RMAX  16512
#define PBLK  64    // persistent blocks per XCD (2 blocks/CU)

typedef __attribute__((ext_vector_type(4)))  float  f32x4;
typedef __attribute__((ext_vector_type(16))) float  f32x16;
typedef __attribute__((ext_vector_type(8)))  __bf16 bf16x8;

__device__ __forceinline__ unsigned short f2bf(float f) {
    unsigned u = __float_as_uint(f);
    u = (u + 0x7fffu + ((u >> 16) & 1u)) >> 16;   // RNE
    return (unsigned short)u;
}

// exact-gelu via Abramowitz-Stegun 7.1.26 erf (|abs err| <= 1.5e-7)
__device__ __forceinline__ float gelu_f(float v) {
    float x  = v * 0.70710678118654752f;
    float ax = fabsf(x);
    float t  = 1.0f / (1.0f + 0.3275911f * ax);
    float poly = ((((1.061405429f * t - 1.453152027f) * t + 1.421413741f) * t
                   - 0.284496736f) * t + 0.254829592f) * t;
    float er = 1.0f - poly * __expf(-x * x);
    er = copysignf(er, x);
    return 0.5f * v * (1.0f + er);
}

__device__ __forceinline__ void gld_lds16(const void* g, void* l) {
    __builtin_amdgcn_global_load_lds(
        (const __attribute__((address_space(1))) unsigned int*)g,
        (__attribute__((address_space(3))) unsigned int*)l, 16, 0, 0);
}

// ---------------- weight fp32 [e][R][C] -> bf16 transposed [e][C][R], merged w1+w2 ----------------
__global__ __launch_bounds__(256) void transpose_cvt2(const float* __restrict__ W1,
                                                      const float* __restrict__ W2,
                                                      unsigned short* __restrict__ W1t,
                                                      unsigned short* __restrict__ W2t) {
    __shared__ unsigned short st[64][72];
    int z = blockIdx.z;
    int R = (z < NE) ? HIDD : FFND;
    int C = (z < NE) ? FFND : HIDD;
    int e = (z < NE) ? z : z - NE;
    if (blockIdx.x >= (unsigned)(C / 64) || blockIdx.y >= (unsigned)(R / 64)) return;
    const float* W = (z < NE) ? W1 : W2;
    unsigned short* Wt = (z < NE) ? W1t : W2t;

    int r0 = blockIdx.y * 64, c0 = blockIdx.x * 64;
    int tid = threadIdx.x;
    int rb = tid >> 4, cq = tid & 15;
    const float* src = W + ((size_t)e * R + r0) * C + c0;
#pragma unroll
    for (int i = 0; i < 4; i++) {
        int kr = i * 16 + rb;
        float4 v = *reinterpret_cast<const float4*>(src + (size_t)kr * C + cq * 4);
        st[cq * 4 + 0][kr] = f2bf(v.x);
        st[cq * 4 + 1][kr] = f2bf(v.y);
        st[cq * 4 + 2][kr] = f2bf(v.z);
        st[cq * 4 + 3][kr] = f2bf(v.w);
    }
    __syncthreads();
    unsigned short* dst = Wt + ((size_t)e * C + c0) * R + r0;
#pragma unroll
    for (int i = 0; i < 4; i++) {
        int cr = i * 16 + rb;
        uint2 v = *reinterpret_cast<const uint2*>(&st[cr][cq * 4]);
        *reinterpret_cast<uint2*>(dst + (size_t)cr * R + cq * 4) = v;
    }
}

// ---------------- fused router + x->bf16 ----------------
__global__ __launch_bounds__(256) void router_kernel(const float* __restrict__ x,
                                                     const float* __restrict__ rw,
                                                     unsigned short* __restrict__ xbf,
                                                     int* __restrict__ cnt,
                                                     int* __restrict__ tok,
                                                     float* __restrict__ gate) {
    __shared__ float4 rwl[2048];
    __shared__ int   e0s[32], e1s[32];
    __shared__ float g0s[32], g1s[32];
    __shared__ int   baseS[16];

    int tid = threadIdx.x, lane = tid & 63, w = tid >> 6;
    for (int i = tid; i < 2048; i += 256) rwl[i] = reinterpret_cast<const float4*>(rw)[i];
    __syncthreads();

    int tbase = blockIdx.x * 32 + w * 8;
    for (int i = 0; i < 8; i++) {
        int t = tbase + i;
        const float4* xr = reinterpret_cast<const float4*>(x) + (size_t)t * 256;
        float4 xv[4];
#pragma unroll
        for (int c = 0; c < 4; c++) xv[c] = xr[c * 64 + lane];
        uint2* xb = reinterpret_cast<uint2*>(xbf) + (size_t)t * 256;
#pragma unroll
        for (int c = 0; c < 4; c++) {
            uint2 p;
            p.x = (unsigned)f2bf(xv[c].x) | ((unsigned)f2bf(xv[c].y) << 16);
            p.y = (unsigned)f2bf(xv[c].z) | ((unsigned)f2bf(xv[c].w) << 16);
            xb[c * 64 + lane] = p;
        }
        float dot[NE];
#pragma unroll
        for (int e = 0; e < NE; e++) {
            float s = 0.f;
#pragma unroll
            for (int c = 0; c < 4; c++) {
                float4 a = rwl[e * 256 + c * 64 + lane];
                s += xv[c].x * a.x + xv[c].y * a.y + xv[c].z * a.z + xv[c].w * a.w;
            }
            dot[e] = s;
        }
#pragma unroll
        for (int e = 0; e < NE; e++) {
            float v = dot[e];
#pragma unroll
            for (int o = 32; o > 0; o >>= 1) v += __shfl_xor(v, o, 64);
            dot[e] = v;
        }
        if (lane == 0) {
            int e0 = 0; float l0 = dot[0];
#pragma unroll
            for (int e = 1; e < NE; e++) if (dot[e] > l0) { l0 = dot[e]; e0 = e; }
            int e1 = -1; float l1 = -3.4e38f;
#pragma unroll
            for (int e = 0; e < NE; e++) if (e != e0 && dot[e] > l1) { l1 = dot[e]; e1 = e; }
            float g0 = 1.f / (1.f + expf(l1 - l0));
            int j = w * 8 + i;
            e0s[j] = e0; e1s[j] = e1; g0s[j] = g0; g1s[j] = 1.f - g0;
        }
    }
    __syncthreads();

    int e0 = 255, e1 = 255, rank0 = 0, rank1 = 0, slotcnt = 0;
    float g0 = 0.f, g1 = 0.f;
    if (w == 0) {
        if (lane < 32) { e0 = e0s[lane]; e1 = e1s[lane]; g0 = g0s[lane]; g1 = g1s[lane]; }
        unsigned long long lt = (1ull << lane) - 1ull;
#pragma unroll
        for (int ee = 0; ee < NE; ee++) {
            unsigned long long m0 = __ballot(e0 == ee);
            unsigned long long m1 = __ballot(e1 == ee);
            if (e0 == ee) rank0 = (int)__popcll(m0 & lt);
            if (e1 == ee) rank1 = (int)__popcll(m1 & lt);
            if (lane == ee)      slotcnt = (int)__popcll(m0);
            if (lane == NE + ee) slotcnt = (int)__popcll(m1);
        }
        if (lane < 16) baseS[lane] = atomicAdd(&cnt[lane * 16], slotcnt);
    }
    __syncthreads();
    if (w == 0 && lane < 32) {
        int t = blockIdx.x * 32 + lane;
        int p0 = baseS[e0] + rank0;
        if (p0 < CAP) { tok[e0 * CAP + p0] = t; gate[e0 * CAP + p0] = g0; }
        int p1 = baseS[NE + e1] + rank1;
        if (p1 < CAP) { tok[(NE + e1) * CAP + p1] = t; gate[(NE + e1) * CAP + p1] = g1; }
    }
}

// ======== persistent 128x256 GEMM, BK=64, 32x32x16 core, wave tile 64x128 (2x4) ========
// 4 waves (2 row-halves x 2 col-halves); per wave: mi=2 (32-row groups), ni=4 (32-col groups).
// Operand reuse: fa x4 MFMA, fb x2 MFMA -> LDS frag reads 0.75KB/MFMA (was 1.0).
// LDS 48KB static (A 16KB + B 32KB), ~2 blocks/CU. Swizzle/decode identical to R11/R13.
template <int KD, int ND, int KS, int CH, bool G1F>
__global__ __launch_bounds__(256, 2) void ffn_gemm_q(const unsigned short* __restrict__ A,
                                                     const unsigned short* __restrict__ Bw, // [e][n][k]
                                                     unsigned short* __restrict__ H,
                                                     float* __restrict__ O,
                                                     const int* __restrict__ cntAll,
                                                     const int* __restrict__ tokL,
                                                     const float* __restrict__ gateL) {
    constexpr int TN    = ND / 256;
    constexpr int UNITS = TN * KS;
    constexpr int KDS   = KD / KS;

    __shared__ __align__(16) unsigned short At[128 * 64];   // 16 KB
    __shared__ __align__(16) unsigned short Bt[256 * 64];   // 32 KB

    int e  = blockIdx.x & 7;
    int pb = blockIdx.x >> 3;

    int cnt0 = min(cntAll[e * 16], CAP);
    int cnt1 = min(cntAll[(e + 8) * 16], CAP);
    int tmx0 = (cnt0 + 127) >> 7, tmx1 = (cnt1 + 127) >> 7;
    int tmsum = tmx0 + tmx1;
    if (tmsum == 0) return;
    int per_chunk = tmsum * CH;
    int total = tmsum * UNITS;

    int offA = 0, offB = 0;
#pragma unroll
    for (int t = 0; t < 16; t++) {
        int cc = min(cntAll[t * 16], CAP);
        if (t < e)     offA += cc;
        if (t < e + 8) offB += cc;
    }

    int tid = threadIdx.x;
    int w = tid >> 6, l = tid & 63;
    int wr = w >> 1, wc = w & 1;

    // ---- staging geometry: sweep j covers rows j*32 + (tid>>3), chunk tid&7; src pre-swizzled
    int sr  = tid >> 3;
    int ssw = (((tid & 7) ^ ((tid >> 4) & 7)) << 4);
    char* aD[4];
    char* bD[8];
#pragma unroll
    for (int j = 0; j < 4; j++) aD[j] = (char*)At + j * 4096 + w * 1024;
#pragma unroll
    for (int j = 0; j < 8; j++) bD[j] = (char*)Bt + j * 4096 + w * 1024;

    // ---- fragment-read offsets ----
    int l31 = l & 31, hi = l >> 5;
    int s8  = (l31 >> 1) & 7;
    int kt[4];
#pragma unroll
    for (int kh = 0; kh < 4; kh++) kt[kh] = (((kh * 2 + hi) ^ s8) << 4);
    int aRdB[2], bRdB[4];
#pragma unroll
    for (int mi = 0; mi < 2; mi++) aRdB[mi] = (wr * 64 + mi * 32 + l31) * 128;
#pragma unroll
    for (int ni = 0; ni < 4; ni++) bRdB[ni] = (wc * 128 + ni * 32 + l31) * 128;

    for (int u0 = pb; u0 < total; u0 += PBLK) {
        int c = u0 / per_chunk;
        int r = u0 - c * per_chunk;
        int s, tm, cnt_e, off_e;
        if (r < tmx0 * CH) { s = e;     tm = r / CH; r -= tm * CH; cnt_e = cnt0; off_e = offA; }
        else { r -= tmx0 * CH; s = e + 8; tm = r / CH; r -= tm * CH; cnt_e = cnt1; off_e = offB; }
        int u  = c * CH + r;
        int tn = (KS > 1) ? (u / KS) : u;
        int ks = (KS > 1) ? (u % KS) : 0;
        const int lbase = s * CAP;

        const char* aS[4];
        const char* bS[8];
#pragma unroll
        for (int j = 0; j < 4; j++) {
            int p = tm * 128 + j * 32 + sr;
            int rowg;
            if (G1F) rowg = tokL[lbase + (p < cnt_e ? p : 0)];
            else     rowg = off_e + p;
            aS[j] = (const char*)(A + (size_t)rowg * KD + ks * KDS) + ssw;
        }
#pragma unroll
        for (int j = 0; j < 8; j++)
            bS[j] = (const char*)(Bw + ((size_t)e * ND + tn * 256 + j * 32 + sr) * KD + ks * KDS) + ssw;

        f32x16 acc[2][4];
#pragma unroll
        for (int mi = 0; mi < 2; mi++)
#pragma unroll
            for (int ni = 0; ni < 4; ni++)
#pragma unroll
                for (int i = 0; i < 16; i++) acc[mi][ni][i] = 0.f;

        for (int k0 = 0; k0 < KDS; k0 += 64) {
            size_t kb = (size_t)k0 * 2;
#pragma unroll
            for (int j = 0; j < 4; j++) gld_lds16(aS[j] + kb, aD[j]);
#pragma unroll
            for (int j = 0; j < 8; j++) gld_lds16(bS[j] + kb, bD[j]);
            __syncthreads();
            const char* Atc = (const char*)At;
            const char* Btc = (const char*)Bt;
#pragma unroll
            for (int kh = 0; kh < 4; kh++) {
                bf16x8 fa[2], fb[4];
#pragma unroll
                for (int mi = 0; mi < 2; mi++)
                    fa[mi] = *reinterpret_cast<const bf16x8*>(Atc + aRdB[mi] + kt[kh]);
#pragma unroll
                for (int ni = 0; ni < 4; ni++)
                    fb[ni] = *reinterpret_cast<const bf16x8*>(Btc + bRdB[ni] + kt[kh]);
#pragma unroll
                for (int mi = 0; mi < 2; mi++)
#pragma unroll
                    for (int ni = 0; ni < 4; ni++)
                        acc[mi][ni] = __builtin_amdgcn_mfma_f32_32x32x16_bf16(fa[mi], fb[ni], acc[mi][ni], 0, 0, 0);
            }
            __syncthreads();
        }

        // ---- epilogue: row = (reg&3) + 8*(reg>>2) + 4*hi ----
#pragma unroll
        for (int mi = 0; mi < 2; mi++) {
#pragma unroll
            for (int reg = 0; reg < 16; reg++) {
                int rr = wr * 64 + mi * 32 + (reg & 3) + 8 * (reg >> 2) + 4 * hi;
                int p  = tm * 128 + rr;
                if (p < cnt_e) {
                    if (G1F) {
                        unsigned short* hp = H + (size_t)(off_e + p) * ND + tn * 256 + wc * 128 + l31;
#pragma unroll
                        for (int ni = 0; ni < 4; ni++) hp[ni * 32] = f2bf(gelu_f(acc[mi][ni][reg]));
                    } else {
                        int t = tokL[lbase + p];
                        float gv = gateL[lbase + p];
                        float* op = O + (size_t)t * ND + tn * 256 + wc * 128 + l31;
#pragma unroll
                        for (int ni = 0; ni < 4; ni++) atomicAdd(op + ni * 32, gv * acc[mi][ni][reg]);
                    }
                }
            }
        }
    }
}

// ======== FALLBACK path (fp32 weights on the fly; used only if ws is small) ========
template <int KD, int ND, bool G1>
__global__ __launch_bounds__(256) void ffn_gemm(const unsigned short* __restrict__ A,
                                                const float* __restrict__ W,
                                                unsigned short* __restrict__ H,
                                                float* __restrict__ O,
                                                const int* __restrict__ cntAll,
                                                const int* __restrict__ tokL,
                                                const float* __restrict__ gateL,
                                                int slot0, int pbase) {
    constexpr int TN = ND / 128;
    int bid = blockIdx.x;
    int tn  = bid % TN;
    int tme = bid / TN;
    int tm  = tme % TMX;
    int s   = slot0 + tme / TMX;
    int eW  = s & 7;
    int cnt_e = min(cntAll[s * 16], CAP);
    if (tm * 128 >= cnt_e) return;
    int off_e = 0;
#pragma unroll
    for (int i = 0; i < 16; i++) {
        int c = min(cntAll[i * 16], CAP);
        off_e += (i >= pbase && i < s) ? c : 0;
    }
    const int lbase = s * CAP;

    __shared__ __align__(16) unsigned short At[128 * 32];
    __shared__ __align__(16) unsigned short Bt[128 * 32];

    int tid = threadIdx.x;
    int w = tid >> 6, l = tid & 63;
    int wr = w >> 1, wc = w & 1;

    int r1 = tid >> 2, q1 = tid & 3;
    int r2 = r1 + 64;
    const char* aSrc1;
    const char* aSrc2;
    if (G1) {
        int p1 = tm * 128 + r1, p2 = tm * 128 + r2;
        int t1 = tokL[lbase + (p1 < cnt_e ? p1 : 0)];
        int t2 = tokL[lbase + (p2 < cnt_e ? p2 : 0)];
        aSrc1 = (const char*)(A + (size_t)t1 * KD) + ((q1 ^ ((r1 >> 1) & 3)) << 4);
        aSrc2 = (const char*)(A + (size_t)t2 * KD) + ((q1 ^ ((r2 >> 1) & 3)) << 4);
    } else {
        size_t row1 = (size_t)off_e + tm * 128 + r1;
        size_t row2 = row1 + 64;
        aSrc1 = (const char*)(A + row1 * KD) + ((q1 ^ ((r1 >> 1) & 3)) << 4);
        aSrc2 = (const char*)(A + row2 * KD) + ((q1 ^ ((r2 >> 1) & 3)) << 4);
    }
    char* aDst1 = (char*)At + w * 1024;
    char* aDst2 = aDst1 + 4096;

    const float* bSrc[4];
    int bOff[16];
#pragma unroll
    for (int j = 0; j < 4; j++) {
        int fidx = j * 1024 + tid * 4;
        int kk = fidx >> 7, n = fidx & 127;
        bSrc[j] = W + (size_t)eW * KD * ND + (size_t)kk * ND + tn * 128 + n;
#pragma unroll
        for (int i = 0; i < 4; i++) {
            int nn = n + i;
            bOff[j * 4 + i] = nn * 64 + ((((kk >> 3) ^ ((nn >> 1) & 3))) << 4) + ((kk & 7) << 1);
        }
    }

    int aro[4], bro[4];
#pragma unroll
    for (int m = 0; m < 4; m++) {
        int rr = wr * 64 + m * 16 + (l & 15);
        aro[m] = rr * 64 + (((l >> 4) ^ ((rr >> 1) & 3)) << 4);
        int cc = wc * 64 + m * 16 + (l & 15);
        bro[m] = cc * 64 + (((l >> 4) ^ ((cc >> 1) & 3)) << 4);
    }

    f32x4 zf = {0.f, 0.f, 0.f, 0.f};
    f32x4 acc[4][4];
#pragma unroll
    for (int m = 0; m < 4; m++)
#pragma unroll
        for (int n = 0; n < 4; n++) acc[m][n] = zf;

    for (int k0 = 0; k0 < KD; k0 += 32) {
        gld_lds16(aSrc1 + (size_t)k0 * 2, aDst1);
        gld_lds16(aSrc2 + (size_t)k0 * 2, aDst2);
        float4 bv[4];
#pragma unroll
        for (int j = 0; j < 4; j++) bv[j] = *reinterpret_cast<const float4*>(bSrc[j] + (size_t)k0 * ND);
        char* btc = (char*)Bt;
#pragma unroll
        for (int j = 0; j < 4; j++) {
            *(unsigned short*)(btc + bOff[j * 4 + 0]) = f2bf(bv[j].x);
            *(unsigned short*)(btc + bOff[j * 4 + 1]) = f2bf(bv[j].y);
            *(unsigned short*)(btc + bOff[j * 4 + 2]) = f2bf(bv[j].z);
            *(unsigned short*)(btc + bOff[j * 4 + 3]) = f2bf(bv[j].w);
        }
        __syncthreads();
        bf16x8 af[4], bf[4];
#pragma unroll
        for (int m = 0; m < 4; m++) af[m] = *reinterpret_cast<const bf16x8*>((const char*)At + aro[m]);
#pragma unroll
        for (int n = 0; n < 4; n++) bf[n] = *reinterpret_cast<const bf16x8*>((const char*)Bt + bro[n]);
#pragma unroll
        for (int m = 0; m < 4; m++)
#pragma unroll
            for (int n = 0; n < 4; n++)
                acc[m][n] = __builtin_amdgcn_mfma_f32_16x16x32_bf16(af[m], bf[n], acc[m][n], 0, 0, 0);
        __syncthreads();
    }

    if (G1) {
#pragma unroll
        for (int m = 0; m < 4; m++) {
#pragma unroll
            for (int j = 0; j < 4; j++) {
                int rr = wr * 64 + m * 16 + (l >> 4) * 4 + j;
                int p = tm * 128 + rr;
                if (p < cnt_e) {
                    size_t row = (size_t)(off_e + p);
                    unsigned short* hp = H + row * ND + tn * 128 + wc * 64 + (l & 15);
#pragma unroll
                    for (int n = 0; n < 4; n++) hp[n * 16] = f2bf(gelu_f(acc[m][n][j]));
                }
            }
        }
    } else {
#pragma unroll
        for (int m = 0; m < 4; m++) {
#pragma unroll
            for (int j = 0; j < 4; j++) {
                int rr = wr * 64 + m * 16 + (l >> 4) * 4 + j;
                int p = tm * 128 + rr;
                if (p < cnt_e) {
                    int t = tokL[lbase + p];
                    float gv = gateL[lbase + p];
                    float* op = O + (size_t)t * ND + tn * 128 + wc * 64 + (l & 15);
#pragma unroll
                    for (int n = 0; n < 4; n++) atomicAdd(op + n * 16, gv * acc[m][n][j]);
                }
            }
        }
    }
}

extern "C" void kernel_launch(void* const* d_in, const int* in_sizes, int n_in,
                              void* d_out, int out_size, void* d_ws, size_t ws_size,
                              hipStream_t stream) {
    const float* x  = (const float*)d_in[0];
    const float* rw = (const float*)d_in[1];
    const float* w1 = (const float*)d_in[2];
    const float* w2 = (const float*)d_in[3];
    float* out = (float*)d_out;
    char* ws = (char*)d_ws;

    int*   cnt  = (int*)ws;                       // 16 counters, 64B apart
    int*   tok  = (int*)(ws + 4096);              // 16*2560 ints
    float* gate = (float*)(ws + 4096 + 16 * CAP * 4);
    unsigned short* xbf = (unsigned short*)(ws + (1 << 20));
    size_t hOff = (1 << 20) + (size_t)N_TOK * HIDD * 2;
    unsigned short* h = (unsigned short*)(ws + hOff);

    size_t w1tSz = (size_t)NE * HIDD * FFND * 2;
    size_t hBig = (size_t)RMAX * FFND * 2;
    size_t needBig = hOff + hBig + 2 * w1tSz;

    hipMemsetAsync(cnt, 0, 1024, stream);
    hipMemsetAsync(d_out, 0, (size_t)N_TOK * HIDD * 4, stream);

    hipLaunchKernelGGL(router_kernel, dim3(N_TOK / 32), dim3(256), 0, stream,
                       x, rw, xbf, cnt, tok, gate);

    if (ws_size >= needBig) {
        unsigned short* w1t = (unsigned short*)(ws + hOff + hBig);
        unsigned short* w2t = (unsigned short*)(ws + hOff + hBig + w1tSz);
        hipLaunchKernelGGL(transpose_cvt2, dim3(FFND / 64, FFND / 64, 2 * NE), dim3(256), 0, stream,
                           w1, w2, w1t, w2t);
        // G1: persistent, 128x256 block, wave 64x128, gelu -> h. UNITS = 16 tn
        hipLaunchKernelGGL((ffn_gemm_q<HIDD, FFND, 1, 4, true>), dim3(8 * PBLK), dim3(256), 0, stream,
                           xbf, w1t, h, (float*)nullptr, cnt, tok, gate);
        // G2: persistent, 128x256 block, KS=2 (4 tn x 2 ks), atomic scatter -> out
        hipLaunchKernelGGL((ffn_gemm_q<FFND, HIDD, 2, 2, false>), dim3(8 * PBLK), dim3(256), 0, stream,
                           h, w2t, (unsigned short*)nullptr, out, cnt, tok, gate);
    } else {
        for (int k = 0; k < 2; k++) {
            hipLaunchKernelGGL((ffn_gemm<HIDD, FFND, true>), dim3(8 * TMX * (FFND / 128)), dim3(256), 0, stream,
                               xbf, w1, h, (float*)nullptr, cnt, tok, gate, 8 * k, 8 * k);
            hipLaunchKernelGGL((ffn_gemm<FFND, HIDD, false>), dim3(8 * TMX * (HIDD / 128)), dim3(256), 0, stream,
                               h, w2, (unsigned short*)nullptr, out, cnt, tok, gate, 8 * k, 8 * k);
        }
    }
}

// Round 15
// 521.457 us; speedup vs baseline: 1.1273x; 1.1273x over previous
//
#include <hip/hip_runtime.h>
#include <hip/hip_bf16.h>
#include <math.h>

#define N_TOK 8192
#define HIDD  1024
#define FFND  4096
#define NE    8
#define CAP   2560
#define TMX   20    // CAP/128 (fallback kernel)
#define RMAX  16512
#define PBLK  128   // persistent blocks per XCD

typedef __attribute__((ext_vector_type(4)))  float  f32x4;
typedef __attribute__((ext_vector_type(16))) float  f32x16;
typedef __attribute__((ext_vector_type(8)))  __bf16 bf16x8;

__device__ __forceinline__ unsigned short f2bf(float f) {
    unsigned u = __float_as_uint(f);
    u = (u + 0x7fffu + ((u >> 16) & 1u)) >> 16;   // RNE
    return (unsigned short)u;
}

// exact-gelu via Abramowitz-Stegun 7.1.26 erf (|abs err| <= 1.5e-7)
__device__ __forceinline__ float gelu_f(float v) {
    float x  = v * 0.70710678118654752f;
    float ax = fabsf(x);
    float t  = 1.0f / (1.0f + 0.3275911f * ax);
    float poly = ((((1.061405429f * t - 1.453152027f) * t + 1.421413741f) * t
                   - 0.284496736f) * t + 0.254829592f) * t;
    float er = 1.0f - poly * __expf(-x * x);
    er = copysignf(er, x);
    return 0.5f * v * (1.0f + er);
}

__device__ __forceinline__ void gld_lds16(const void* g, void* l) {
    __builtin_amdgcn_global_load_lds(
        (const __attribute__((address_space(1))) unsigned int*)g,
        (__attribute__((address_space(3))) unsigned int*)l, 16, 0, 0);
}

// ---------------- weight fp32 [e][R][C] -> bf16 transposed [e][C][R] ----------------
template <int R, int C>
__global__ __launch_bounds__(256) void transpose_cvt(const float* __restrict__ W,
                                                     unsigned short* __restrict__ Wt) {
    __shared__ unsigned short st[64][72];
    int e  = blockIdx.z;
    int r0 = blockIdx.y * 64, c0 = blockIdx.x * 64;
    int tid = threadIdx.x;
    int rb = tid >> 4, cq = tid & 15;
    const float* src = W + ((size_t)e * R + r0) * C + c0;
#pragma unroll
    for (int i = 0; i < 4; i++) {
        int kr = i * 16 + rb;
        float4 v = *reinterpret_cast<const float4*>(src + (size_t)kr * C + cq * 4);
        st[cq * 4 + 0][kr] = f2bf(v.x);
        st[cq * 4 + 1][kr] = f2bf(v.y);
        st[cq * 4 + 2][kr] = f2bf(v.z);
        st[cq * 4 + 3][kr] = f2bf(v.w);
    }
    __syncthreads();
    unsigned short* dst = Wt + ((size_t)e * C + c0) * R + r0;
#pragma unroll
    for (int i = 0; i < 4; i++) {
        int cr = i * 16 + rb;
        uint2 v = *reinterpret_cast<const uint2*>(&st[cr][cq * 4]);
        *reinterpret_cast<uint2*>(dst + (size_t)cr * R + cq * 4) = v;
    }
}

// ---------------- fused router + x->bf16 ----------------
__global__ __launch_bounds__(256) void router_kernel(const float* __restrict__ x,
                                                     const float* __restrict__ rw,
                                                     unsigned short* __restrict__ xbf,
                                                     int* __restrict__ cnt,
                                                     int* __restrict__ tok,
                                                     float* __restrict__ gate) {
    __shared__ float4 rwl[2048];
    __shared__ int   e0s[32], e1s[32];
    __shared__ float g0s[32], g1s[32];
    __shared__ int   baseS[16];

    int tid = threadIdx.x, lane = tid & 63, w = tid >> 6;
    for (int i = tid; i < 2048; i += 256) rwl[i] = reinterpret_cast<const float4*>(rw)[i];
    __syncthreads();

    int tbase = blockIdx.x * 32 + w * 8;
    for (int i = 0; i < 8; i++) {
        int t = tbase + i;
        const float4* xr = reinterpret_cast<const float4*>(x) + (size_t)t * 256;
        float4 xv[4];
#pragma unroll
        for (int c = 0; c < 4; c++) xv[c] = xr[c * 64 + lane];
        uint2* xb = reinterpret_cast<uint2*>(xbf) + (size_t)t * 256;
#pragma unroll
        for (int c = 0; c < 4; c++) {
            uint2 p;
            p.x = (unsigned)f2bf(xv[c].x) | ((unsigned)f2bf(xv[c].y) << 16);
            p.y = (unsigned)f2bf(xv[c].z) | ((unsigned)f2bf(xv[c].w) << 16);
            xb[c * 64 + lane] = p;
        }
        float dot[NE];
#pragma unroll
        for (int e = 0; e < NE; e++) {
            float s = 0.f;
#pragma unroll
            for (int c = 0; c < 4; c++) {
                float4 a = rwl[e * 256 + c * 64 + lane];
                s += xv[c].x * a.x + xv[c].y * a.y + xv[c].z * a.z + xv[c].w * a.w;
            }
            dot[e] = s;
        }
#pragma unroll
        for (int e = 0; e < NE; e++) {
            float v = dot[e];
#pragma unroll
            for (int o = 32; o > 0; o >>= 1) v += __shfl_xor(v, o, 64);
            dot[e] = v;
        }
        if (lane == 0) {
            int e0 = 0; float l0 = dot[0];
#pragma unroll
            for (int e = 1; e < NE; e++) if (dot[e] > l0) { l0 = dot[e]; e0 = e; }
            int e1 = -1; float l1 = -3.4e38f;
#pragma unroll
            for (int e = 0; e < NE; e++) if (e != e0 && dot[e] > l1) { l1 = dot[e]; e1 = e; }
            float g0 = 1.f / (1.f + expf(l1 - l0));
            int j = w * 8 + i;
            e0s[j] = e0; e1s[j] = e1; g0s[j] = g0; g1s[j] = 1.f - g0;
        }
    }
    __syncthreads();

    int e0 = 255, e1 = 255, rank0 = 0, rank1 = 0, slotcnt = 0;
    float g0 = 0.f, g1 = 0.f;
    if (w == 0) {
        if (lane < 32) { e0 = e0s[lane]; e1 = e1s[lane]; g0 = g0s[lane]; g1 = g1s[lane]; }
        unsigned long long lt = (1ull << lane) - 1ull;
#pragma unroll
        for (int ee = 0; ee < NE; ee++) {
            unsigned long long m0 = __ballot(e0 == ee);
            unsigned long long m1 = __ballot(e1 == ee);
            if (e0 == ee) rank0 = (int)__popcll(m0 & lt);
            if (e1 == ee) rank1 = (int)__popcll(m1 & lt);
            if (lane == ee)      slotcnt = (int)__popcll(m0);
            if (lane == NE + ee) slotcnt = (int)__popcll(m1);
        }
        if (lane < 16) baseS[lane] = atomicAdd(&cnt[lane * 16], slotcnt);
    }
    __syncthreads();
    if (w == 0 && lane < 32) {
        int t = blockIdx.x * 32 + lane;
        int p0 = baseS[e0] + rank0;
        if (p0 < CAP) { tok[e0 * CAP + p0] = t; gate[e0 * CAP + p0] = g0; }
        int p1 = baseS[NE + e1] + rank1;
        if (p1 < CAP) { tok[(NE + e1) * CAP + p1] = t; gate[(NE + e1) * CAP + p1] = g1; }
    }
}

// ======== persistent 128x128 GEMM, BK=64, 32x32x16 MFMA core (both GEMMs) ========
// 4 waves 2x2, wave tile 64x64 = 2x2 of 32x32. LDS 2x16KB. ~4 blocks/CU.
// LDS row = 128B (8 chunks); swizzle: chunk c of row r stored at c ^ ((r>>1)&7).
// C/D: col=l&31, row=(reg&3)+8*(reg>>2)+4*(l>>5)  [HW-verified m74/m101]
template <int KD, int ND, int KS, int CH, bool G1F>
__global__ __launch_bounds__(256, 4) void ffn_gemm_q(const unsigned short* __restrict__ A,
                                                     const unsigned short* __restrict__ Bw, // [e][n][k]
                                                     unsigned short* __restrict__ H,
                                                     float* __restrict__ O,
                                                     const int* __restrict__ cntAll,
                                                     const int* __restrict__ tokL,
                                                     const float* __restrict__ gateL) {
    constexpr int TN    = ND / 128;
    constexpr int UNITS = TN * KS;
    constexpr int KDS   = KD / KS;

    __shared__ __align__(16) unsigned short At[128 * 64];
    __shared__ __align__(16) unsigned short Bt[128 * 64];

    int e  = blockIdx.x & 7;
    int pb = blockIdx.x >> 3;

    int cnt0 = min(cntAll[e * 16], CAP);
    int cnt1 = min(cntAll[(e + 8) * 16], CAP);
    int tmx0 = (cnt0 + 127) >> 7, tmx1 = (cnt1 + 127) >> 7;
    int tmsum = tmx0 + tmx1;
    if (tmsum == 0) return;
    int per_chunk = tmsum * CH;
    int total = tmsum * UNITS;

    int offA = 0, offB = 0;
#pragma unroll
    for (int t = 0; t < 16; t++) {
        int cc = min(cntAll[t * 16], CAP);
        if (t < e)     offA += cc;
        if (t < e + 8) offB += cc;
    }

    int tid = threadIdx.x;
    int w = tid >> 6, l = tid & 63;
    int wr = w >> 1, wc = w & 1;

    // ---- staging geometry: sweep j covers rows j*32 + (tid>>3), chunk tid&7; src pre-swizzled
    int sr  = tid >> 3;
    int ssw = (((tid & 7) ^ ((tid >> 4) & 7)) << 4);
    char* aD[4];
    char* bD[4];
#pragma unroll
    for (int j = 0; j < 4; j++) {
        aD[j] = (char*)At + j * 4096 + w * 1024;
        bD[j] = (char*)Bt + j * 4096 + w * 1024;
    }

    // ---- fragment-read offsets (hoisted; unit-independent) ----
    int l31 = l & 31, hi = l >> 5;
    int s8  = (l31 >> 1) & 7;
    int kt[4];
#pragma unroll
    for (int kh = 0; kh < 4; kh++) kt[kh] = (((kh * 2 + hi) ^ s8) << 4);
    int aRdB[2], bRdB[2];
#pragma unroll
    for (int mi = 0; mi < 2; mi++) {
        aRdB[mi] = (wr * 64 + mi * 32 + l31) * 128;
        bRdB[mi] = (wc * 64 + mi * 32 + l31) * 128;
    }

    for (int u0 = pb; u0 < total; u0 += PBLK) {
        int c = u0 / per_chunk;
        int r = u0 - c * per_chunk;
        int s, tm, cnt_e, off_e;
        if (r < tmx0 * CH) { s = e;     tm = r / CH; r -= tm * CH; cnt_e = cnt0; off_e = offA; }
        else { r -= tmx0 * CH; s = e + 8; tm = r / CH; r -= tm * CH; cnt_e = cnt1; off_e = offB; }
        int u  = c * CH + r;
        int tn = (KS > 1) ? (u / KS) : u;
        int ks = (KS > 1) ? (u % KS) : 0;
        const int lbase = s * CAP;

        const char* aS[4];
        const char* bS[4];
#pragma unroll
        for (int j = 0; j < 4; j++) {
            int p = tm * 128 + j * 32 + sr;
            int rowg;
            if (G1F) rowg = tokL[lbase + (p < cnt_e ? p : 0)];
            else     rowg = off_e + p;
            aS[j] = (const char*)(A + (size_t)rowg * KD + ks * KDS) + ssw;
            bS[j] = (const char*)(Bw + ((size_t)e * ND + tn * 128 + j * 32 + sr) * KD + ks * KDS) + ssw;
        }

        f32x16 a00, a01, a10, a11;
#pragma unroll
        for (int i = 0; i < 16; i++) { a00[i] = 0.f; a01[i] = 0.f; a10[i] = 0.f; a11[i] = 0.f; }

        for (int k0 = 0; k0 < KDS; k0 += 64) {
            size_t kb = (size_t)k0 * 2;
#pragma unroll
            for (int j = 0; j < 4; j++) gld_lds16(aS[j] + kb, aD[j]);
#pragma unroll
            for (int j = 0; j < 4; j++) gld_lds16(bS[j] + kb, bD[j]);
            __syncthreads();
            const char* Atc = (const char*)At;
            const char* Btc = (const char*)Bt;
#pragma unroll
            for (int kh = 0; kh < 4; kh++) {
                bf16x8 fa0 = *reinterpret_cast<const bf16x8*>(Atc + aRdB[0] + kt[kh]);
                bf16x8 fa1 = *reinterpret_cast<const bf16x8*>(Atc + aRdB[1] + kt[kh]);
                bf16x8 fb0 = *reinterpret_cast<const bf16x8*>(Btc + bRdB[0] + kt[kh]);
                bf16x8 fb1 = *reinterpret_cast<const bf16x8*>(Btc + bRdB[1] + kt[kh]);
                a00 = __builtin_amdgcn_mfma_f32_32x32x16_bf16(fa0, fb0, a00, 0, 0, 0);
                a01 = __builtin_amdgcn_mfma_f32_32x32x16_bf16(fa0, fb1, a01, 0, 0, 0);
                a10 = __builtin_amdgcn_mfma_f32_32x32x16_bf16(fa1, fb0, a10, 0, 0, 0);
                a11 = __builtin_amdgcn_mfma_f32_32x32x16_bf16(fa1, fb1, a11, 0, 0, 0);
            }
            __syncthreads();
        }

        // ---- epilogue: row = (reg&3) + 8*(reg>>2) + 4*hi ----
#pragma unroll
        for (int mi = 0; mi < 2; mi++) {
#pragma unroll
            for (int reg = 0; reg < 16; reg++) {
                int rr = wr * 64 + mi * 32 + (reg & 3) + 8 * (reg >> 2) + 4 * hi;
                int p  = tm * 128 + rr;
                if (p < cnt_e) {
                    float v0 = (mi == 0) ? a00[reg] : a10[reg];
                    float v1 = (mi == 0) ? a01[reg] : a11[reg];
                    if (G1F) {
                        unsigned short* hp = H + (size_t)(off_e + p) * ND + tn * 128 + wc * 64 + l31;
                        hp[0]  = f2bf(gelu_f(v0));
                        hp[32] = f2bf(gelu_f(v1));
                    } else {
                        int t = tokL[lbase + p];
                        float gv = gateL[lbase + p];
                        float* op = O + (size_t)t * ND + tn * 128 + wc * 64 + l31;
                        atomicAdd(op,      gv * v0);
                        atomicAdd(op + 32, gv * v1);
                    }
                }
            }
        }
    }
}

// ======== FALLBACK path (fp32 weights on the fly; used only if ws is small) ========
template <int KD, int ND, bool G1>
__global__ __launch_bounds__(256) void ffn_gemm(const unsigned short* __restrict__ A,
                                                const float* __restrict__ W,
                                                unsigned short* __restrict__ H,
                                                float* __restrict__ O,
                                                const int* __restrict__ cntAll,
                                                const int* __restrict__ tokL,
                                                const float* __restrict__ gateL,
                                                int slot0, int pbase) {
    constexpr int TN = ND / 128;
    int bid = blockIdx.x;
    int tn  = bid % TN;
    int tme = bid / TN;
    int tm  = tme % TMX;
    int s   = slot0 + tme / TMX;
    int eW  = s & 7;
    int cnt_e = min(cntAll[s * 16], CAP);
    if (tm * 128 >= cnt_e) return;
    int off_e = 0;
#pragma unroll
    for (int i = 0; i < 16; i++) {
        int c = min(cntAll[i * 16], CAP);
        off_e += (i >= pbase && i < s) ? c : 0;
    }
    const int lbase = s * CAP;

    __shared__ __align__(16) unsigned short At[128 * 32];
    __shared__ __align__(16) unsigned short Bt[128 * 32];

    int tid = threadIdx.x;
    int w = tid >> 6, l = tid & 63;
    int wr = w >> 1, wc = w & 1;

    int r1 = tid >> 2, q1 = tid & 3;
    int r2 = r1 + 64;
    const char* aSrc1;
    const char* aSrc2;
    if (G1) {
        int p1 = tm * 128 + r1, p2 = tm * 128 + r2;
        int t1 = tokL[lbase + (p1 < cnt_e ? p1 : 0)];
        int t2 = tokL[lbase + (p2 < cnt_e ? p2 : 0)];
        aSrc1 = (const char*)(A + (size_t)t1 * KD) + ((q1 ^ ((r1 >> 1) & 3)) << 4);
        aSrc2 = (const char*)(A + (size_t)t2 * KD) + ((q1 ^ ((r2 >> 1) & 3)) << 4);
    } else {
        size_t row1 = (size_t)off_e + tm * 128 + r1;
        size_t row2 = row1 + 64;
        aSrc1 = (const char*)(A + row1 * KD) + ((q1 ^ ((r1 >> 1) & 3)) << 4);
        aSrc2 = (const char*)(A + row2 * KD) + ((q1 ^ ((r2 >> 1) & 3)) << 4);
    }
    char* aDst1 = (char*)At + w * 1024;
    char* aDst2 = aDst1 + 4096;

    const float* bSrc[4];
    int bOff[16];
#pragma unroll
    for (int j = 0; j < 4; j++) {
        int fidx = j * 1024 + tid * 4;
        int kk = fidx >> 7, n = fidx & 127;
        bSrc[j] = W + (size_t)eW * KD * ND + (size_t)kk * ND + tn * 128 + n;
#pragma unroll
        for (int i = 0; i < 4; i++) {
            int nn = n + i;
            bOff[j * 4 + i] = nn * 64 + ((((kk >> 3) ^ ((nn >> 1) & 3))) << 4) + ((kk & 7) << 1);
        }
    }

    int aro[4], bro[4];
#pragma unroll
    for (int m = 0; m < 4; m++) {
        int rr = wr * 64 + m * 16 + (l & 15);
        aro[m] = rr * 64 + (((l >> 4) ^ ((rr >> 1) & 3)) << 4);
        int cc = wc * 64 + m * 16 + (l & 15);
        bro[m] = cc * 64 + (((l >> 4) ^ ((cc >> 1) & 3)) << 4);
    }

    f32x4 zf = {0.f, 0.f, 0.f, 0.f};
    f32x4 acc[4][4];
#pragma unroll
    for (int m = 0; m < 4; m++)
#pragma unroll
        for (int n = 0; n < 4; n++) acc[m][n] = zf;

    for (int k0 = 0; k0 < KD; k0 += 32) {
        gld_lds16(aSrc1 + (size_t)k0 * 2, aDst1);
        gld_lds16(aSrc2 + (size_t)k0 * 2, aDst2);
        float4 bv[4];
#pragma unroll
        for (int j = 0; j < 4; j++) bv[j] = *reinterpret_cast<const float4*>(bSrc[j] + (size_t)k0 * ND);
        char* btc = (char*)Bt;
#pragma unroll
        for (int j = 0; j < 4; j++) {
            *(unsigned short*)(btc + bOff[j * 4 + 0]) = f2bf(bv[j].x);
            *(unsigned short*)(btc + bOff[j * 4 + 1]) = f2bf(bv[j].y);
            *(unsigned short*)(btc + bOff[j * 4 + 2]) = f2bf(bv[j].z);
            *(unsigned short*)(btc + bOff[j * 4 + 3]) = f2bf(bv[j].w);
        }
        __syncthreads();
        bf16x8 af[4], bf[4];
#pragma unroll
        for (int m = 0; m < 4; m++) af[m] = *reinterpret_cast<const bf16x8*>((const char*)At + aro[m]);
#pragma unroll
        for (int n = 0; n < 4; n++) bf[n] = *reinterpret_cast<const bf16x8*>((const char*)Bt + bro[n]);
#pragma unroll
        for (int m = 0; m < 4; m++)
#pragma unroll
            for (int n = 0; n < 4; n++)
                acc[m][n] = __builtin_amdgcn_mfma_f32_16x16x32_bf16(af[m], bf[n], acc[m][n], 0, 0, 0);
        __syncthreads();
    }

    if (G1) {
#pragma unroll
        for (int m = 0; m < 4; m++) {
#pragma unroll
            for (int j = 0; j < 4; j++) {
                int rr = wr * 64 + m * 16 + (l >> 4) * 4 + j;
                int p = tm * 128 + rr;
                if (p < cnt_e) {
                    size_t row = (size_t)(off_e + p);
                    unsigned short* hp = H + row * ND + tn * 128 + wc * 64 + (l & 15);
#pragma unroll
                    for (int n = 0; n < 4; n++) hp[n * 16] = f2bf(gelu_f(acc[m][n][j]));
                }
            }
        }
    } else {
#pragma unroll
        for (int m = 0; m < 4; m++) {
#pragma unroll
            for (int j = 0; j < 4; j++) {
                int rr = wr * 64 + m * 16 + (l >> 4) * 4 + j;
                int p = tm * 128 + rr;
                if (p < cnt_e) {
                    int t = tokL[lbase + p];
                    float gv = gateL[lbase + p];
                    float* op = O + (size_t)t * ND + tn * 128 + wc * 64 + (l & 15);
#pragma unroll
                    for (int n = 0; n < 4; n++) atomicAdd(op + n * 16, gv * acc[m][n][j]);
                }
            }
        }
    }
}

extern "C" void kernel_launch(void* const* d_in, const int* in_sizes, int n_in,
                              void* d_out, int out_size, void* d_ws, size_t ws_size,
                              hipStream_t stream) {
    const float* x  = (const float*)d_in[0];
    const float* rw = (const float*)d_in[1];
    const float* w1 = (const float*)d_in[2];
    const float* w2 = (const float*)d_in[3];
    float* out = (float*)d_out;
    char* ws = (char*)d_ws;

    int*   cnt  = (int*)ws;                       // 16 counters, 64B apart
    int*   tok  = (int*)(ws + 4096);              // 16*2560 ints
    float* gate = (float*)(ws + 4096 + 16 * CAP * 4);
    unsigned short* xbf = (unsigned short*)(ws + (1 << 20));
    size_t hOff = (1 << 20) + (size_t)N_TOK * HIDD * 2;
    unsigned short* h = (unsigned short*)(ws + hOff);

    size_t w1tSz = (size_t)NE * HIDD * FFND * 2;
    size_t hBig = (size_t)RMAX * FFND * 2;
    size_t needBig = hOff + hBig + 2 * w1tSz;

    hipMemsetAsync(cnt, 0, 1024, stream);
    hipMemsetAsync(d_out, 0, (size_t)N_TOK * HIDD * 4, stream);

    hipLaunchKernelGGL(router_kernel, dim3(N_TOK / 32), dim3(256), 0, stream,
                       x, rw, xbf, cnt, tok, gate);

    if (ws_size >= needBig) {
        unsigned short* w1t = (unsigned short*)(ws + hOff + hBig);
        unsigned short* w2t = (unsigned short*)(ws + hOff + hBig + w1tSz);
        hipLaunchKernelGGL((transpose_cvt<HIDD, FFND>), dim3(FFND / 64, HIDD / 64, NE), dim3(256), 0, stream, w1, w1t);
        hipLaunchKernelGGL((transpose_cvt<FFND, HIDD>), dim3(HIDD / 64, FFND / 64, NE), dim3(256), 0, stream, w2, w2t);
        // G1: persistent, 32x32 core, gelu -> h
        hipLaunchKernelGGL((ffn_gemm_q<HIDD, FFND, 1, 8, true>), dim3(8 * PBLK), dim3(256), 0, stream,
                           xbf, w1t, h, (float*)nullptr, cnt, tok, gate);
        // G2: persistent, 32x32 core, KS=2, atomic scatter -> out
        hipLaunchKernelGGL((ffn_gemm_q<FFND, HIDD, 2, 4, false>), dim3(8 * PBLK), dim3(256), 0, stream,
                           h, w2t, (unsigned short*)nullptr, out, cnt, tok, gate);
    } else {
        for (int k = 0; k < 2; k++) {
            hipLaunchKernelGGL((ffn_gemm<HIDD, FFND, true>), dim3(8 * TMX * (FFND / 128)), dim3(256), 0, stream,
                               xbf, w1, h, (float*)nullptr, cnt, tok, gate, 8 * k, 8 * k);
            hipLaunchKernelGGL((ffn_gemm<FFND, HIDD, false>), dim3(8 * TMX * (HIDD / 128)), dim3(256), 0, stream,
                               h, w2, (unsigned short*)nullptr, out, cnt, tok, gate, 8 * k, 8 * k);
        }
    }
}